// Round 5
// baseline (209.907 us; speedup 1.0000x reference)
//
#include <hip/hip_runtime.h>

#define BN 1024
#define NV 6890
#define NBETA 10
#define PB 207            // pose basis = 9*(J-1)
#define N3 20670          // NV*3
#define NCOL 20736        // 108*192 padded GEMM columns
#define NCHUNK 7          // K = 224 = 207 pose + 10 betas + 1 template + 6 zero
#define BT 32             // batches per k_vert block

typedef __bf16 bf16x8 __attribute__((ext_vector_type(8)));
typedef float  f32x4  __attribute__((ext_vector_type(4)));

__device__ __constant__ int c_par[24] = {-1,0,0,0,1,2,3,4,5,6,7,8,9,9,9,12,13,14,16,17,18,19,20,21};

__device__ inline unsigned short f2bf(float f) {
    unsigned u = __float_as_uint(f);
    u += 0x7fff + ((u >> 16) & 1);          // RNE
    return (unsigned short)(u >> 16);
}

// quad butterfly add via DPP (VALU pipe, no LDS)
__device__ inline float quad_reduce_add(float x) {
    int a = __builtin_amdgcn_update_dpp(0, __float_as_int(x), 0xB1, 0xF, 0xF, true); // [1,0,3,2]
    float x2 = x + __int_as_float(a);
    int b = __builtin_amdgcn_update_dpp(0, __float_as_int(x2), 0x4E, 0xF, 0xF, true); // [2,3,0,1]
    return x2 + __int_as_float(b);
}

// ---------------------------------------------------------------------------
// k_prep, 4 disjoint block ranges:
//  A [0,567):      pdt2[col][224] bf16 = (posedirs ; shapedirs^T ; v_template ; 0)
//  B [567,799):    pose_feature+betas+1 -> ws_pfb[b][232] bf16
//  C [799,1069):   lbs weights -> ws_wb[v][40] bf16 (v<6912)
//  D [1069,1261):  J_regressor partials (per-joint, coalesced sd) -> ws_jsp
// ---------------------------------------------------------------------------
__global__ __launch_bounds__(256) void k_prep(const float* __restrict__ pd,
                                              const float* __restrict__ sd,
                                              const float* __restrict__ vtm,
                                              const float* __restrict__ Jr,
                                              const float* __restrict__ bpose,
                                              const float* __restrict__ betas,
                                              const float* __restrict__ w,
                                              unsigned short* __restrict__ ws_pdt,
                                              unsigned short* __restrict__ ws_pfb,
                                              unsigned short* __restrict__ ws_wb,
                                              float* __restrict__ ws_jsp)
{
    int blk = blockIdx.x;
    if (blk < 567) {
        int kc = blk / 81;
        int col = (blk - kc * 81) * 256 + threadIdx.x;   // 0..20735
        bool cok = col < N3;
        unsigned short vals[32];
        #pragma unroll
        for (int kk = 0; kk < 32; kk++) {
            int gk = kc * 32 + kk;
            float val = 0.f;
            if (cok) {
                if (gk < PB)             val = pd[(size_t)gk * N3 + col];
                else if (gk < PB + 10)   val = sd[(size_t)col * NBETA + (gk - PB)];
                else if (gk == PB + 10)  val = vtm[col];
            }
            vals[kk] = f2bf(val);
        }
        uint4* dst = (uint4*)(ws_pdt + (size_t)col * 224 + kc * 32);
        #pragma unroll
        for (int q = 0; q < 4; q++) {
            uint4 u;
            u.x = vals[q*8+0] | ((unsigned)vals[q*8+1] << 16);
            u.y = vals[q*8+2] | ((unsigned)vals[q*8+3] << 16);
            u.z = vals[q*8+4] | ((unsigned)vals[q*8+5] << 16);
            u.w = vals[q*8+6] | ((unsigned)vals[q*8+7] << 16);
            dst[q] = u;
        }
    } else if (blk < 799) {
        int e0 = (blk - 567) * 1024 + threadIdx.x * 4;   // 232*1024 total
        unsigned short v4[4];
        #pragma unroll
        for (int r = 0; r < 4; r++) {
            int e = e0 + r;
            int b = e / 232, k = e - b * 232;
            float x = 0.f;
            if (k < PB) {
                x = bpose[(size_t)b * PB + k];
                int k9 = k % 9;
                if (k9 == 0 || k9 == 4 || k9 == 8) x -= 1.f;
            } else if (k < PB + 10) {
                x = betas[b * NBETA + (k - PB)];
            } else if (k == PB + 10) {
                x = 1.f;
            }
            v4[r] = f2bf(x);
        }
        uint2 u;
        u.x = v4[0] | ((unsigned)v4[1] << 16);
        u.y = v4[2] | ((unsigned)v4[3] << 16);
        *(uint2*)(ws_pfb + e0) = u;
    } else if (blk < 1069) {
        int e0 = (blk - 799) * 1024 + threadIdx.x * 4;   // 6912*40 total
        unsigned short v4[4];
        #pragma unroll
        for (int r = 0; r < 4; r++) {
            int e = e0 + r;
            int v = e / 40, j = e - v * 40;
            float val = (j < 24 && v < NV) ? w[(size_t)v * 24 + j] : 0.f;
            v4[r] = f2bf(val);
        }
        uint2 u;
        u.x = v4[0] | ((unsigned)v4[1] << 16);
        u.y = v4[2] | ((unsigned)v4[3] << 16);
        *(uint2*)(ws_wb + e0) = u;
    } else {
        // D: block (j, seg): acc[c][l] over vertex segment, sd read contiguously
        int b2 = blk - 1069;           // 0..191
        int j = b2 >> 3;               // 0..23
        int seg = b2 & 7;              // 0..7
        int v0 = seg * 862;
        int v1 = v0 + 862; if (v1 > NV) v1 = NV;

        float acc[33];
        #pragma unroll
        for (int l = 0; l < 33; l++) acc[l] = 0.f;

        for (int v = v0 + threadIdx.x; v < v1; v += 256) {
            float r = Jr[j * NV + v];
            const float* s = sd + (size_t)v * 30;
            #pragma unroll
            for (int c = 0; c < 3; c++) {
                #pragma unroll
                for (int l = 0; l < NBETA; l++)
                    acc[c * 11 + l] += r * s[c * 10 + l];
                acc[c * 11 + 10] += r * vtm[v * 3 + c];
            }
        }

        __shared__ float red[4][33];
        int lane = threadIdx.x & 63, wv = threadIdx.x >> 6;
        #pragma unroll
        for (int l = 0; l < 33; l++) {
            float x = acc[l];
            x += __shfl_down(x, 32, 64);
            x += __shfl_down(x, 16, 64);
            x += __shfl_down(x, 8, 64);
            x += __shfl_down(x, 4, 64);
            x += __shfl_down(x, 2, 64);
            x += __shfl_down(x, 1, 64);
            if (lane == 0) red[wv][l] = x;
        }
        __syncthreads();
        if (threadIdx.x < 33)
            ws_jsp[(size_t)seg * 792 + j * 33 + threadIdx.x] =
                red[0][threadIdx.x] + red[1][threadIdx.x] +
                red[2][threadIdx.x] + red[3][threadIdx.x];
    }
}

// ---------------------------------------------------------------------------
// k_chain: 64 blocks x 256 threads, 16 batches/block (16 lanes per batch).
// ---------------------------------------------------------------------------
__global__ __launch_bounds__(256) void k_chain(const float* __restrict__ betas,
                                               const float* __restrict__ grot,
                                               const float* __restrict__ bpose,
                                               const float* __restrict__ ws_jsp,
                                               unsigned short* __restrict__ ws_artb,
                                               float* __restrict__ pj)
{
    __shared__ float js_s[72 * 11];
    __shared__ float jt[16][72];
    __shared__ float tl[16][288];
    __shared__ float am[16][288];
    int tid = threadIdx.x;

    for (int e = tid; e < 72 * 11; e += 256) {
        float s = 0.f;
        #pragma unroll
        for (int seg = 0; seg < 8; seg++)
            s += ws_jsp[(size_t)seg * 792 + e];
        js_s[e] = s;
    }
    __syncthreads();

    int lb = tid >> 4;              // 0..15
    int e  = tid & 15;              // 0..15
    int b  = blockIdx.x * 16 + lb;

    for (int idx = e; idx < 72; idx += 16) {
        float acc = js_s[idx * 11 + 10];
        const float* be = betas + b * NBETA;
        #pragma unroll
        for (int l = 0; l < NBETA; l++) acc += be[l] * js_s[idx * 11 + l];
        jt[lb][idx] = acc;
    }
    __syncthreads();

    for (int idx = e; idx < 288; idx += 16) {
        int j = idx / 12, e12 = idx % 12, m = e12 >> 2, n = e12 & 3;
        float val;
        if (n < 3) {
            val = (j == 0) ? grot[(size_t)b * 9 + m * 3 + n]
                           : bpose[((size_t)b * 23 + (j - 1)) * 9 + m * 3 + n];
        } else {
            val = jt[lb][j * 3 + m];
            if (j > 0) val -= jt[lb][c_par[j] * 3 + m];
        }
        tl[lb][idx] = val;
    }
    __syncthreads();

    if (e < 12) am[lb][e] = tl[lb][e];
    for (int i = 1; i < 24; i++) {
        __syncthreads();
        if (e < 12) {
            int p = c_par[i];
            int m = e >> 2, n = e & 3;
            float val = am[lb][p*12 + m*4 + 0] * tl[lb][i*12 + 0 + n]
                      + am[lb][p*12 + m*4 + 1] * tl[lb][i*12 + 4 + n]
                      + am[lb][p*12 + m*4 + 2] * tl[lb][i*12 + 8 + n];
            if (n == 3) val += am[lb][p*12 + m*4 + 3];
            am[lb][i*12 + e] = val;
        }
    }
    __syncthreads();

    for (int idx = e; idx < 72; idx += 16) {
        int j = idx / 3, m = idx % 3;
        pj[(size_t)b * 72 + idx] = am[lb][j*12 + m*4 + 3];
    }
    // ArT[b][col=m*4+n][j'] bf16, j' 0..39 (24..39 zero)
    for (int idx = e; idx < 480; idx += 16) {
        int col = idx / 40, j = idx - col * 40;
        float val = 0.f;
        if (j < 24) {
            int m = col >> 2, n = col & 3;
            if (n < 3) {
                val = am[lb][j*12 + col];
            } else {
                val = am[lb][j*12 + m*4 + 3]
                    - am[lb][j*12 + m*4 + 0] * jt[lb][j*3 + 0]
                    - am[lb][j*12 + m*4 + 1] * jt[lb][j*3 + 1]
                    - am[lb][j*12 + m*4 + 2] * jt[lb][j*3 + 2];
            }
        }
        ws_artb[(size_t)b * 480 + idx] = f2bf(val);
    }
}

// ---------------------------------------------------------------------------
// k_vert: phase 1 = MFMA GEMM, B-frags DIRECT from global (no LDS staging,
// no K-loop syncs). phase 2 = T-MFMA (ArT frags direct from global) + DPP
// quad-reduce epilogue (no T_l round-trip). LDS: disp3 (v*163+b*5+nn, with
// embedded 1.0) + double-buffered out_l = 48 KB -> 3 blocks/CU.
// ---------------------------------------------------------------------------
__global__ __launch_bounds__(256, 3) void k_vert(const unsigned short* __restrict__ ws_pdt,
                                                 const unsigned short* __restrict__ ws_pfb,
                                                 const unsigned short* __restrict__ ws_wb,
                                                 const unsigned short* __restrict__ ws_artb,
                                                 float* __restrict__ out)
{
    const int bb = blockIdx.x;            // 0..31
    const int vb = blockIdx.y;            // 0..107
    const int tid = threadIdx.x;
    const int wv = tid >> 6;
    const int lane = tid & 63;
    const int r16 = lane & 15;
    const int quad = lane >> 4;
    const int half8 = quad * 8;

    __shared__ float disp3[10432];        // [v]*163 + [b]*5 + nn ; nn=3 holds 1.0
    __shared__ float out_l[2][4 * 196];

    // ---------------- phase 1: v_posed GEMM, all operands from global -------
    const unsigned short* pfbase = ws_pfb + (size_t)(bb * BT) * 232;
    const unsigned short* pdbase = ws_pdt + (size_t)(vb * 192 + wv * 48) * 224;

    f32x4 acc[2][3];
    #pragma unroll
    for (int mt = 0; mt < 2; mt++)
        #pragma unroll
        for (int t = 0; t < 3; t++)
            acc[mt][t] = (f32x4){0.f, 0.f, 0.f, 0.f};

    #pragma unroll
    for (int kc = 0; kc < NCHUNK; kc++) {
        bf16x8 a0 = *(const bf16x8*)(pfbase + r16 * 232 + kc * 32 + half8);
        bf16x8 a1 = *(const bf16x8*)(pfbase + (16 + r16) * 232 + kc * 32 + half8);
        bf16x8 b0 = *(const bf16x8*)(pdbase + (size_t)r16 * 224 + kc * 32 + half8);
        bf16x8 b1 = *(const bf16x8*)(pdbase + (size_t)(16 + r16) * 224 + kc * 32 + half8);
        bf16x8 b2 = *(const bf16x8*)(pdbase + (size_t)(32 + r16) * 224 + kc * 32 + half8);
        acc[0][0] = __builtin_amdgcn_mfma_f32_16x16x32_bf16(a0, b0, acc[0][0], 0, 0, 0);
        acc[1][0] = __builtin_amdgcn_mfma_f32_16x16x32_bf16(a1, b0, acc[1][0], 0, 0, 0);
        acc[0][1] = __builtin_amdgcn_mfma_f32_16x16x32_bf16(a0, b1, acc[0][1], 0, 0, 0);
        acc[1][1] = __builtin_amdgcn_mfma_f32_16x16x32_bf16(a1, b1, acc[1][1], 0, 0, 0);
        acc[0][2] = __builtin_amdgcn_mfma_f32_16x16x32_bf16(a0, b2, acc[0][2], 0, 0, 0);
        acc[1][2] = __builtin_amdgcn_mfma_f32_16x16x32_bf16(a1, b2, acc[1][2], 0, 0, 0);
    }

    // scatter v_posed into disp3; bank = (col + 5b) % 32 -> 2-way max
    #pragma unroll
    for (int mt = 0; mt < 2; mt++) {
        #pragma unroll
        for (int t = 0; t < 3; t++) {
            int col = wv * 48 + t * 16 + r16;
            int vloc = col / 3, c = col - vloc * 3;
            int brow = mt * 16 + quad * 4;
            #pragma unroll
            for (int r = 0; r < 4; r++)
                disp3[vloc * 163 + (brow + r) * 5 + c] = acc[mt][t][r];
        }
    }
    // embedded homogeneous 1.0
    #pragma unroll
    for (int i = 0; i < 8; i++) {
        int e = tid + i * 256;            // 0..2047
        int v = e >> 5, b = e & 31;
        disp3[v * 163 + b * 5 + 3] = 1.f;
    }
    __syncthreads();

    // ---------------- phase 2: LBS via T-MFMA + DPP reduce ------------------
    bf16x8 aw = *(const bf16x8*)(ws_wb + (size_t)(vb * 64 + wv * 16 + r16) * 40 + half8);

    const int q16 = r16 >> 2;
    const int sel = r16 & 3;              // which i this lane stores (3 = idle)
    // (b,m) this lane stores, for i = sel (valid when sel<3)
    int gsel = sel * 16 + q16 * 4;
    int bq = gsel / 12;
    int mq = (gsel - 12 * bq) >> 2;
    // (b_l, nn) per i for the multiply
    int bl[3], nn[3];
    #pragma unroll
    for (int i = 0; i < 3; i++) {
        int g = i * 16 + r16;
        bl[i] = g / 12;
        nn[i] = (g - 12 * bl[i]) & 3;
    }

    for (int sub = 0; sub < 8; sub++) {
        const unsigned short* Abase = ws_artb + ((size_t)(bb * BT + sub * 4) * 12) * 40;
        bf16x8 bA0 = *(const bf16x8*)(Abase + (size_t)r16 * 40 + half8);
        bf16x8 bA1 = *(const bf16x8*)(Abase + (size_t)(16 + r16) * 40 + half8);
        bf16x8 bA2 = *(const bf16x8*)(Abase + (size_t)(32 + r16) * 40 + half8);
        f32x4 z = (f32x4){0.f, 0.f, 0.f, 0.f};
        f32x4 t0 = __builtin_amdgcn_mfma_f32_16x16x32_bf16(aw, bA0, z, 0, 0, 0);
        f32x4 t1 = __builtin_amdgcn_mfma_f32_16x16x32_bf16(aw, bA1, z, 0, 0, 0);
        f32x4 t2 = __builtin_amdgcn_mfma_f32_16x16x32_bf16(aw, bA2, z, 0, 0, 0);

        int buf = sub & 1;
        #pragma unroll
        for (int r = 0; r < 4; r++) {
            int vloc = wv * 16 + quad * 4 + r;
            int vbase = vloc * 163 + (sub * 4) * 5;
            float s0 = quad_reduce_add(t0[r] * disp3[vbase + bl[0] * 5 + nn[0]]);
            float s1 = quad_reduce_add(t1[r] * disp3[vbase + bl[1] * 5 + nn[1]]);
            float s2 = quad_reduce_add(t2[r] * disp3[vbase + bl[2] * 5 + nn[2]]);
            float sv = (sel == 0) ? s0 : ((sel == 1) ? s1 : s2);
            if (sel < 3)
                out_l[buf][bq * 196 + vloc * 3 + mq] = sv;
        }
        __syncthreads();

        // coalesced flush of this sub's 4 batches
        for (int e = tid; e < 4 * 192; e += 256) {
            int b_l = e / 192, idx = e - b_l * 192;
            int gcol = vb * 192 + idx;
            if (gcol < N3)
                out[((size_t)(bb * BT + sub * 4 + b_l)) * N3 + gcol] = out_l[buf][b_l * 196 + idx];
        }
        // no extra sync: next sub writes buf^1; flush of this buf is
        // program-ordered before the next __syncthreads for the same buf reuse
    }
}

// ---------------------------------------------------------------------------
extern "C" void kernel_launch(void* const* d_in, const int* in_sizes, int n_in,
                              void* d_out, int out_size, void* d_ws, size_t ws_size,
                              hipStream_t stream) {
    const float* betas = (const float*)d_in[0];
    const float* grot  = (const float*)d_in[1];
    const float* bpose = (const float*)d_in[2];
    const float* vtm   = (const float*)d_in[3];
    const float* sd    = (const float*)d_in[4];
    const float* pd    = (const float*)d_in[5];
    const float* Jr    = (const float*)d_in[6];
    const float* w     = (const float*)d_in[7];
    float* out = (float*)d_out;

    char* ws = (char*)d_ws;
    unsigned short* ws_pdt  = (unsigned short*)(ws);              // 20736*224*2 = 9,289,728
    unsigned short* ws_pfb  = (unsigned short*)(ws + 9289728);    //    475,136
    unsigned short* ws_wb   = (unsigned short*)(ws + 9764864);    //    552,960
    float*          ws_jsp  = (float*)         (ws + 10317824);   //     25,344
    unsigned short* ws_artb = (unsigned short*)(ws + 10343168);   //    983,040

    k_prep<<<1261, 256, 0, stream>>>(pd, sd, vtm, Jr, bpose, betas, w,
                                     ws_pdt, ws_pfb, ws_wb, ws_jsp);
    k_chain<<<BN / 16, 256, 0, stream>>>(betas, grot, bpose, ws_jsp, ws_artb,
                                         out + (size_t)BN * N3);
    k_vert<<<dim3(32, 108), 256, 0, stream>>>(ws_pdt, ws_pfb, ws_wb, ws_artb, out);
}